// Round 1
// baseline (121.720 us; speedup 1.0000x reference)
//
#include <hip/hip_runtime.h>

#define EPS_ 1e-6f
constexpr int B_ = 16, N_ = 256, D_ = 4, K_ = 10, C_ = 100;
constexpr int CP = 128;   // padded C for LDS tiles

// ---------------------------------------------------------------------------
// Kernel 1: xk[b][k][m][c] = sum_j x[b,m,k*C+j] * W[c,j] + bias[c]
// x viewed as A[R][C] with R = B*N*K rows (row r = (b*N+m)*K + k, contiguous!)
// Block: 64 rows x 100 cols (padded to 128). 256 threads, 4x8 reg tile.
// ---------------------------------------------------------------------------
__global__ __launch_bounds__(256) void xk_gemm(
    const float* __restrict__ x, const float* __restrict__ W,
    const float* __restrict__ bias, float* __restrict__ xk)
{
    __shared__ float A_lds[64][101];   // [row][j], +1 pad
    __shared__ float WT_lds[100][CP];  // [j][c], transposed W, zero-padded c>=100

    const int tid = threadIdx.x;
    const int r0  = blockIdx.x * 64;

    // stage A: fully coalesced (rows are contiguous in x)
    const float* Ab = x + (size_t)r0 * C_;
    #pragma unroll 1
    for (int idx = tid; idx < 64 * C_; idx += 256) {
        A_lds[idx / C_][idx % C_] = Ab[idx];
    }
    // stage W transposed: strided global reads (40KB, L1/L2-hot), conflict-free LDS writes
    #pragma unroll 1
    for (int idx = tid; idx < C_ * CP; idx += 256) {
        int j = idx >> 7, c = idx & (CP - 1);
        WT_lds[j][c] = (c < C_) ? W[c * C_ + j] : 0.0f;
    }
    __syncthreads();

    const int cg = tid & 15, rg = tid >> 4;
    // thread's c columns: j<4 -> 4*cg+j ; j>=4 -> 64+4*cg+(j-4)
    float bv[8];
    #pragma unroll
    for (int j = 0; j < 8; ++j) {
        int c = (j < 4) ? (4 * cg + j) : (64 + 4 * cg + j - 4);
        bv[j] = (c < C_) ? bias[c] : 0.0f;
    }
    float acc[4][8];
    #pragma unroll
    for (int i = 0; i < 4; ++i)
        #pragma unroll
        for (int j = 0; j < 8; ++j) acc[i][j] = bv[j];

    #pragma unroll 2
    for (int jj = 0; jj < C_; ++jj) {
        float av[4];
        #pragma unroll
        for (int i = 0; i < 4; ++i) av[i] = A_lds[rg * 4 + i][jj];
        float4 w0 = *(const float4*)&WT_lds[jj][4 * cg];
        float4 w1 = *(const float4*)&WT_lds[jj][64 + 4 * cg];
        float wv[8] = {w0.x, w0.y, w0.z, w0.w, w1.x, w1.y, w1.z, w1.w};
        #pragma unroll
        for (int i = 0; i < 4; ++i)
            #pragma unroll
            for (int j = 0; j < 8; ++j)
                acc[i][j] = fmaf(av[i], wv[j], acc[i][j]);
    }

    // write xk[b][k][m][c]
    #pragma unroll
    for (int i = 0; i < 4; ++i) {
        int r   = r0 + rg * 4 + i;
        int b   = r / (N_ * K_);
        int rem = r - b * (N_ * K_);
        int m   = rem / K_;
        int k   = rem - m * K_;
        float* dst = xk + ((size_t)(b * K_ + k) * N_ + m) * C_;
        float4 v0 = {acc[i][0], acc[i][1], acc[i][2], acc[i][3]};
        *(float4*)(dst + 4 * cg) = v0;                 // c = 4cg..4cg+3  (<=66 < 100)
        if (cg < 9) {                                   // c = 64+4cg..+3 (< 100 only cg<=8)
            float4 v1 = {acc[i][4], acc[i][5], acc[i][6], acc[i][7]};
            *(float4*)(dst + 64 + 4 * cg) = v1;
        }
    }
}

// ---------------------------------------------------------------------------
// Kernel 2: fused Gaussian + aggregation.
// Block per (b, k, n-tile of 64). Loop m in chunks of 32:
//   phase A: ag[n,m] = adj * exp(sum_d -0.5*(pseudo-mu)^2/(eps+sigma^2)) -> LDS
//   phase B: stage xk[b,k,m0:m0+32, 0:100] -> LDS [32][128] (zero pad)
//   phase C: acc[n_i][c_j] += ag[n][m] * xk[m][c]   (4x8 reg tile / thread)
// Output: out[((b*K+k)*C + c)*N + n]
// ---------------------------------------------------------------------------
__global__ __launch_bounds__(256) void gauss_agg(
    const float* __restrict__ adj, const float* __restrict__ pseudo,
    const float* __restrict__ mu, const float* __restrict__ sigma,
    const float* __restrict__ xk, float* __restrict__ out)
{
    __shared__ float ag_lds[64][33];   // [n_local][m_local], stride 33 (conflict-free)
    __shared__ float xk_lds[32][CP];   // [m_local][c], zero-padded c>=100

    const int tid = threadIdx.x;
    const int n0  = blockIdx.x * 64;
    const int k   = blockIdx.y;
    const int b   = blockIdx.z;

    float muv[D_], coef[D_];
    #pragma unroll
    for (int d = 0; d < D_; ++d) {
        float s  = sigma[k * D_ + d];
        coef[d]  = -0.5f / (EPS_ + s * s);
        muv[d]   = mu[k * D_ + d];
    }

    const float* adj_b = adj + (size_t)b * N_ * N_;
    const float* ps_b  = pseudo + (size_t)b * N_ * N_ * D_;
    const float* xk_bk = xk + (size_t)(b * K_ + k) * N_ * C_;

    const int ml = tid & 31, nb = tid >> 5;   // gaussian-phase mapping
    const int cg = tid & 15, ng = tid >> 4;   // matmul-phase mapping

    float acc[4][8];
    #pragma unroll
    for (int i = 0; i < 4; ++i)
        #pragma unroll
        for (int j = 0; j < 8; ++j) acc[i][j] = 0.0f;

    for (int m0 = 0; m0 < N_; m0 += 32) {
        __syncthreads();   // protect LDS from previous iteration's reads

        // phase A: gaussian edge weights for this (n-tile, m-chunk)
        #pragma unroll
        for (int i = 0; i < 8; ++i) {
            int nl = nb * 8 + i;
            int n  = n0 + nl, m = m0 + ml;
            float4 p = *(const float4*)(ps_b + ((size_t)n * N_ + m) * D_);
            float  a = adj_b[n * N_ + m];
            float dx = p.x - muv[0], dy = p.y - muv[1];
            float dz = p.z - muv[2], dw = p.w - muv[3];
            float s = coef[0] * dx * dx + coef[1] * dy * dy
                    + coef[2] * dz * dz + coef[3] * dw * dw;
            ag_lds[nl][ml] = a * __expf(s);
        }
        // phase B: stage xk chunk
        #pragma unroll 1
        for (int idx = tid; idx < 32 * CP; idx += 256) {
            int m = idx >> 7, c = idx & (CP - 1);
            xk_lds[m][c] = (c < C_) ? xk_bk[(m0 + m) * C_ + c] : 0.0f;
        }
        __syncthreads();

        // phase C: accumulate
        #pragma unroll 4
        for (int m = 0; m < 32; ++m) {
            float av[4];
            #pragma unroll
            for (int i = 0; i < 4; ++i) av[i] = ag_lds[ng * 4 + i][m];
            float4 w0 = *(const float4*)&xk_lds[m][4 * cg];
            float4 w1 = *(const float4*)&xk_lds[m][64 + 4 * cg];
            float wv[8] = {w0.x, w0.y, w0.z, w0.w, w1.x, w1.y, w1.z, w1.w};
            #pragma unroll
            for (int i = 0; i < 4; ++i)
                #pragma unroll
                for (int j = 0; j < 8; ++j)
                    acc[i][j] = fmaf(av[i], wv[j], acc[i][j]);
        }
    }

    // epilogue: out[(b*K+k)*C*N + c*N + n], float4 over the 4 consecutive n's
    float* ob = out + (size_t)(b * K_ + k) * C_ * N_ + n0 + ng * 4;
    #pragma unroll
    for (int j = 0; j < 8; ++j) {
        int c = (j < 4) ? (4 * cg + j) : (64 + 4 * cg + j - 4);
        if (c < C_) {
            float4 v = {acc[0][j], acc[1][j], acc[2][j], acc[3][j]};
            *(float4*)(ob + (size_t)c * N_) = v;
        }
    }
}

extern "C" void kernel_launch(void* const* d_in, const int* in_sizes, int n_in,
                              void* d_out, int out_size, void* d_ws, size_t ws_size,
                              hipStream_t stream)
{
    const float* x      = (const float*)d_in[0];
    const float* adj    = (const float*)d_in[1];
    const float* pseudo = (const float*)d_in[2];
    const float* mu     = (const float*)d_in[3];
    const float* sigma  = (const float*)d_in[4];
    const float* W      = (const float*)d_in[5];
    const float* bias   = (const float*)d_in[6];
    float* out = (float*)d_out;
    float* xk  = (float*)d_ws;   // B*K*N*C floats = 16.4 MB

    hipLaunchKernelGGL(xk_gemm, dim3((B_ * N_ * K_) / 64), dim3(256), 0, stream,
                       x, W, bias, xk);
    hipLaunchKernelGGL(gauss_agg, dim3(N_ / 64, K_, B_), dim3(256), 0, stream,
                       adj, pseudo, mu, sigma, xk, out);
}

// Round 2
// 70.735 us; speedup vs baseline: 1.7208x; 1.7208x over previous
//
#include <hip/hip_runtime.h>

typedef __bf16 bf16;
typedef __attribute__((ext_vector_type(8))) __bf16 bf16x8;
typedef __attribute__((ext_vector_type(4))) float f32x4;

#define EPS_ 1e-6f
constexpr int B_ = 16, N_ = 256, D_ = 4, K_ = 10, C_ = 100;
constexpr int CP_ = 112;   // c rows padded to 7*16 in xkT workspace

// ---------------------------------------------------------------------------
// Kernel 1: xkT[b,k][c][m] = sum_j W[c,j] * x[b,m,k*C+j] + bias[c]   (bf16 out)
//   MFMA GEMM: A = W (c x j), B = x-slice (j x m), D = (c x m).
//   No LDS: A/B fragments loaded straight from global (W is 40KB, L1/L2-hot).
//   Rows c in [100,112) are written as zeros (bias 0, W-frag 0).
// Grid: (mh=2, k=10, b=16), 256 threads = 4 waves; wave owns m-range 32.
// ---------------------------------------------------------------------------
__global__ __launch_bounds__(256) void xkT_mfma(
    const float* __restrict__ x, const float* __restrict__ W,
    const float* __restrict__ bias, bf16* __restrict__ xkT)
{
    const int mh = blockIdx.x, k = blockIdx.y, b = blockIdx.z;
    const int tid = threadIdx.x;
    const int w = tid >> 6, l = tid & 63, l15 = l & 15, g = l >> 4;

    f32x4 acc[7][2];
    #pragma unroll
    for (int ct = 0; ct < 7; ++ct)
        #pragma unroll
        for (int r = 0; r < 4; ++r) {
            int c = ct * 16 + g * 4 + r;
            float bv = (c < C_) ? bias[c] : 0.0f;
            acc[ct][0][r] = bv; acc[ct][1][r] = bv;
        }

    const int m_base = mh * 128 + w * 32;
    const float* xb = x + (size_t)b * N_ * K_ * C_ + k * C_;

    #pragma unroll 1
    for (int ks = 0; ks < 4; ++ks) {
        const int jb = ks * 32 + g * 8;   // this lane's first j

        // A fragments (W rows), shared across both m-tiles
        bf16x8 afrag[7];
        #pragma unroll
        for (int ct = 0; ct < 7; ++ct) {
            int c = ct * 16 + l15;
            bf16x8 af;
            #pragma unroll
            for (int i = 0; i < 8; ++i) af[i] = (bf16)0.0f;
            if (c < C_) {
                const float* wp = W + (size_t)c * C_ + jb;
                if (jb + 8 <= C_) {
                    float4 w0 = *(const float4*)wp;
                    float4 w1 = *(const float4*)(wp + 4);
                    af[0] = (bf16)w0.x; af[1] = (bf16)w0.y; af[2] = (bf16)w0.z; af[3] = (bf16)w0.w;
                    af[4] = (bf16)w1.x; af[5] = (bf16)w1.y; af[6] = (bf16)w1.z; af[7] = (bf16)w1.w;
                } else if (jb < C_) {     // jb == 96: last 4 valid j
                    float4 w0 = *(const float4*)wp;
                    af[0] = (bf16)w0.x; af[1] = (bf16)w0.y; af[2] = (bf16)w0.z; af[3] = (bf16)w0.w;
                }
            }
            afrag[ct] = af;
        }

        // B fragments (x columns) + MFMA
        #pragma unroll
        for (int mt = 0; mt < 2; ++mt) {
            int m = m_base + mt * 16 + l15;
            const float* xp = xb + (size_t)m * K_ * C_ + jb;
            bf16x8 bfr;
            #pragma unroll
            for (int i = 0; i < 8; ++i) bfr[i] = (bf16)0.0f;
            if (jb + 8 <= C_) {
                float4 x0 = *(const float4*)xp;
                float4 x1 = *(const float4*)(xp + 4);
                bfr[0] = (bf16)x0.x; bfr[1] = (bf16)x0.y; bfr[2] = (bf16)x0.z; bfr[3] = (bf16)x0.w;
                bfr[4] = (bf16)x1.x; bfr[5] = (bf16)x1.y; bfr[6] = (bf16)x1.z; bfr[7] = (bf16)x1.w;
            } else if (jb < C_) {
                float4 x0 = *(const float4*)xp;
                bfr[0] = (bf16)x0.x; bfr[1] = (bf16)x0.y; bfr[2] = (bf16)x0.z; bfr[3] = (bf16)x0.w;
            }
            #pragma unroll
            for (int ct = 0; ct < 7; ++ct)
                acc[ct][mt] = __builtin_amdgcn_mfma_f32_16x16x32_bf16(
                    afrag[ct], bfr, acc[ct][mt], 0, 0, 0);
        }
    }

    // store bf16, rows c in [100,112) are zeros by construction
    bf16* op = xkT + (size_t)(b * K_ + k) * CP_ * N_;
    #pragma unroll
    for (int ct = 0; ct < 7; ++ct)
        #pragma unroll
        for (int mt = 0; mt < 2; ++mt) {
            int m = m_base + mt * 16 + l15;
            #pragma unroll
            for (int r = 0; r < 4; ++r) {
                int c = ct * 16 + g * 4 + r;
                op[(size_t)c * N_ + m] = (bf16)acc[ct][mt][r];
            }
        }
}

// ---------------------------------------------------------------------------
// Kernel 2: out[b,k][c][n] = sum_m ag[n,m] * xk[m,c]
//   MFMA: A[n][m] = ag (computed in registers, one exp per element, no LDS,
//   no barriers), B[m][c] = xkT read as bf16x8 straight from workspace.
//   D[n][c]: row=n=(l>>4)*4+r, col=c=l&15  -> scattered 4B stores (16 rows/instr).
// Grid: 640 blocks (XCD-swizzled so each XCD owns 2 batches), 256 thr = 4 waves.
// ---------------------------------------------------------------------------
__global__ __launch_bounds__(256) void gauss_agg_mfma(
    const float* __restrict__ adj, const float* __restrict__ pseudo,
    const float* __restrict__ mu, const float* __restrict__ sigma,
    const bf16* __restrict__ xkT, float* __restrict__ out)
{
    // XCD-aware decode: XCD x gets batches {x, x+8}; (b,k) stays on one XCD.
    const int bid = blockIdx.x;
    const int xcd = bid & 7, slot = bid >> 3;          // slot 0..79
    const int b  = xcd + 8 * (slot / 40);
    const int rr = slot % 40;
    const int k  = rr >> 2, nq = rr & 3;

    const int tid = threadIdx.x;
    const int w = tid >> 6, l = tid & 63, l15 = l & 15, g = l >> 4;
    const int n_tile = nq * 64 + w * 16;

    float muv[4], coef[4];
    #pragma unroll
    for (int d = 0; d < 4; ++d) {
        float s = sigma[k * 4 + d];
        coef[d] = -0.5f / (EPS_ + s * s);
        muv[d]  = mu[k * 4 + d];
    }

    const int n_a = n_tile + l15;  // A-fragment row this lane owns
    const float* adj_row = adj + ((size_t)b * N_ + n_a) * N_;
    const float* ps_row  = pseudo + ((size_t)(b * N_ + n_a) * N_) * 4;
    const bf16*  xs      = xkT + (size_t)(b * K_ + k) * CP_ * N_;

    f32x4 acc[7];
    #pragma unroll
    for (int ct = 0; ct < 7; ++ct)
        #pragma unroll
        for (int r = 0; r < 4; ++r) acc[ct][r] = 0.0f;

    #pragma unroll 1
    for (int ks = 0; ks < 8; ++ks) {
        const int m0 = ks * 32 + g * 8;   // this lane's first m

        float4 a0 = *(const float4*)(adj_row + m0);
        float4 a1 = *(const float4*)(adj_row + m0 + 4);
        float av[8] = {a0.x, a0.y, a0.z, a0.w, a1.x, a1.y, a1.z, a1.w};

        bf16x8 af;
        #pragma unroll
        for (int i = 0; i < 8; ++i) {
            float4 p = *(const float4*)(ps_row + (size_t)(m0 + i) * 4);
            float dx = p.x - muv[0], dy = p.y - muv[1];
            float dz = p.z - muv[2], dw = p.w - muv[3];
            float s = coef[0] * dx * dx + coef[1] * dy * dy
                    + coef[2] * dz * dz + coef[3] * dw * dw;
            af[i] = (bf16)(av[i] * __expf(s));
        }

        #pragma unroll
        for (int ct = 0; ct < 7; ++ct) {
            const bf16* bp = xs + (size_t)(ct * 16 + l15) * N_ + m0;
            bf16x8 bfr = *(const bf16x8*)bp;
            acc[ct] = __builtin_amdgcn_mfma_f32_16x16x32_bf16(af, bfr, acc[ct], 0, 0, 0);
        }
    }

    float* ob = out + (size_t)(b * K_ + k) * C_ * N_;
    #pragma unroll
    for (int ct = 0; ct < 7; ++ct) {
        int c = ct * 16 + l15;
        if (c < C_) {
            #pragma unroll
            for (int r = 0; r < 4; ++r) {
                int n = n_tile + g * 4 + r;
                ob[(size_t)c * N_ + n] = acc[ct][r];
            }
        }
    }
}

extern "C" void kernel_launch(void* const* d_in, const int* in_sizes, int n_in,
                              void* d_out, int out_size, void* d_ws, size_t ws_size,
                              hipStream_t stream)
{
    const float* x      = (const float*)d_in[0];
    const float* adj    = (const float*)d_in[1];
    const float* pseudo = (const float*)d_in[2];
    const float* mu     = (const float*)d_in[3];
    const float* sigma  = (const float*)d_in[4];
    const float* W      = (const float*)d_in[5];
    const float* bias   = (const float*)d_in[6];
    float* out = (float*)d_out;
    bf16* xkT  = (bf16*)d_ws;   // B*K*112*256 bf16 = 9.2 MB

    hipLaunchKernelGGL(xkT_mfma, dim3(2, K_, B_), dim3(256), 0, stream,
                       x, W, bias, xkT);
    hipLaunchKernelGGL(gauss_agg_mfma, dim3(B_ * K_ * 4), dim3(256), 0, stream,
                       adj, pseudo, mu, sigma, xkT, out);
}